// Round 2
// baseline (119.948 us; speedup 1.0000x reference)
//
#include <hip/hip_runtime.h>
#include <hip/hip_bf16.h>

// Problem constants: B=2, T=2048, D=1024, H=16, DK=64
// Math reduction: y = permute(x @ Wv) @ Wo^T  (softmax rowsum == 1 exactly;
// reference's einsum 'bhtl,bthd->bhtd' never contracts v with A over l, so
// o[b,h,t,:] = (sum_l A[b,h,t,l]) * v[b,t,h,:] = v[b,t,h,:]).
// Permute: V[b*2048+t][h*64+k] -> Vp[b*2048 + h*128 + t/16][(t%16)*64 + k]
// R12: fold fp32->bf16 conversions into the GEMMs. gemm1 reads x DIRECTLY
// as fp32 via global_load_lds (cvt at fragment load); gemm2 reads Wo fp32
// the same way. prep shrinks to WvT-transpose only. Removes ~20 MB HBM
// (x: 32->16 MB, Wo: 8->4 MB) and most of prep's time. Geometry = R8/R10
// proven best: 128x64 tile, 4 waves 64x32, 512 blocks (2/CU, 2 waves/SIMD),
// triple-buffer + raw s_barrier + counted vmcnt (5 DMAs/batch for gemm1,
// 4 for gemm2). fp32 LDS tiles use 8-chunk XOR swizzle g = s ^ (r&7)
// (row stride 128B = 32 banks; slot determines bank group; balanced).
// Ledger: R11 (128x128, 64x64/wave) neutral -> inner loop not marginal;
// fixed harness overhead ~64 us; persistent fusion +152 us; fp8 excluded.

using bf16 = __hip_bfloat16;
typedef __attribute__((ext_vector_type(8))) short bf16x8;   // 8 bf16 = 4 VGPRs
typedef __attribute__((ext_vector_type(4))) float f32x4;

__device__ __forceinline__ void gld_lds16(const void* g, void* l) {
    // async global->LDS, 16B/lane; LDS dest = wave-uniform base + lane*16
    __builtin_amdgcn_global_load_lds(
        (const __attribute__((address_space(1))) void*)g,
        (__attribute__((address_space(3))) void*)l, 16, 0, 0);
}

__device__ __forceinline__ bf16x8 cvt8(f32x4 lo, f32x4 hi) {
    bf16 o[8] = {__float2bfloat16(lo[0]), __float2bfloat16(lo[1]),
                 __float2bfloat16(lo[2]), __float2bfloat16(lo[3]),
                 __float2bfloat16(hi[0]), __float2bfloat16(hi[1]),
                 __float2bfloat16(hi[2]), __float2bfloat16(hi[3])};
    return *(bf16x8*)o;
}

// ---- prep: Wv transpose+cvt only (WvT[n][k] = bf16(Wv[k][n])) -------------
__global__ __launch_bounds__(256) void prep(const float* __restrict__ Wv,
                                            bf16* __restrict__ WvT) {
    __shared__ float tile[64][65];
    const int id = blockIdx.x;           // 256 blocks: 16x16 tiles of 64x64
    const int t  = threadIdx.x;
    const int bx = id & 15, by = id >> 4;
    const int c = t & 63, r4 = t >> 6;
#pragma unroll
    for (int p = 0; p < 16; ++p) {
        int r = p * 4 + r4;
        tile[r][c] = Wv[(size_t)(by * 64 + r) * 1024 + bx * 64 + c];
    }
    __syncthreads();
#pragma unroll
    for (int p = 0; p < 16; ++p) {
        int r = p * 4 + r4;
        WvT[(size_t)(bx * 64 + r) * 1024 + by * 64 + c] = __float2bfloat16(tile[c][r]);
    }
}

// ---------------- GEMM  C = A(Mx1024) * Bt(Nx1024)^T -----------------------
// A, Bt row-major [.][K], K-contiguous; either operand may be fp32 (staged
// to LDS as fp32, converted to bf16 at fragment load) or bf16.
// 128x64 tile / 256 threads; 4 waves 2x2, each 64x32 = 4x2 accs.
// Triple-buffered LDS, 2 DMA batches in flight, raw s_barrier + counted vmcnt.
__device__ __forceinline__ void storeC(float v, bf16* p)  { *p = __float2bfloat16(v); }
__device__ __forceinline__ void storeC(float v, float* p) { *p = v; }

template <bool PERMUTE, bool AF32, bool BF32, typename OutT>
__global__ __launch_bounds__(256, 2) void gemm_bt(const void* __restrict__ Av,
                                                  const void* __restrict__ Bv,
                                                  OutT* __restrict__ C) {
    constexpr int ABYTES = AF32 ? 16384 : 8192;   // 128 rows x 32 k
    constexpr int BBYTES = BF32 ? 8192  : 4096;   // 64 rows x 32 k
    constexpr int BUFB   = ABYTES + BBYTES;
    constexpr int NDMA   = (AF32 ? 4 : 2) + (BF32 ? 2 : 1);
    __shared__ __align__(16) char st[3 * BUFB];

    const int tid  = threadIdx.x;
    const int wave = tid >> 6;
    const int lane = tid & 63;
    const int m0 = blockIdx.x * 128;
    const int n0 = blockIdx.y * 64;

    const int wr = (wave >> 1) * 64;      // wave quadrant of 128x64 tile
    const int wc = (wave & 1) * 32;

    // staging source pointers (per-lane, pre-swizzled so LDS stays linear)
    // bf16 tiles: 4 chunks/row, slot s of row r holds chunk s ^ ((r>>1)&3)
    // fp32 tiles: 8 chunks/row, slot s of row r holds chunk s ^ (r&7)
    const float* gA32 = nullptr; const bf16* gAb = nullptr;
    if constexpr (AF32)
        gA32 = (const float*)Av + (size_t)(m0 + (tid >> 3)) * 1024
             + (((tid & 7) ^ ((tid >> 3) & 7)) * 4);
    else
        gAb  = (const bf16*)Av + (size_t)(m0 + (tid >> 2)) * 1024
             + (((tid & 3) ^ ((tid >> 3) & 3)) * 8);
    const float* gB32 = nullptr; const bf16* gBb = nullptr;
    if constexpr (BF32)
        gB32 = (const float*)Bv + (size_t)(n0 + (tid >> 3)) * 1024
             + (((tid & 7) ^ ((tid >> 3) & 7)) * 4);
    else
        gBb  = (const bf16*)Bv + (size_t)(n0 + (tid >> 2)) * 1024
             + (((tid & 3) ^ ((tid >> 3) & 3)) * 8);

    const int wb = wave * 1024;           // bytes, wave-uniform LDS base per DMA

    auto stage = [&](int kt, int buf) {
        char* base = st + buf * BUFB;
        if constexpr (AF32) {
            const float* s = gA32 + kt * 32;
            gld_lds16(s,             base + wb);
            gld_lds16(s + 32 * 1024, base + 4096  + wb);
            gld_lds16(s + 64 * 1024, base + 8192  + wb);
            gld_lds16(s + 96 * 1024, base + 12288 + wb);
        } else {
            const bf16* s = gAb + kt * 32;
            gld_lds16(s,             base + wb);
            gld_lds16(s + 64 * 1024, base + 4096 + wb);
        }
        char* bb = base + ABYTES;
        if constexpr (BF32) {
            const float* s = gB32 + kt * 32;
            gld_lds16(s,             bb + wb);
            gld_lds16(s + 32 * 1024, bb + 4096 + wb);
        } else {
            const bf16* s = gBb + kt * 32;
            gld_lds16(s, bb + wb);
        }
    };

    f32x4 acc[4][2];
#pragma unroll
    for (int i = 0; i < 4; ++i)
#pragma unroll
        for (int j = 0; j < 2; ++j)
            acc[i][j] = (f32x4){0.f, 0.f, 0.f, 0.f};

    const int fr = lane & 15;
    const int q8  = (((lane >> 4) ^ (lane >> 1)) & 3) * 8;     // bf16 read slot
    const int s32 = (((lane >> 4) * 2) ^ (lane & 7)) * 4;      // fp32 read slot (floats)

    // prologue: batches 0,1 -> bufs 0,1 (2*NDMA outstanding per wave)
    stage(0, 0);
    stage(1, 1);

#pragma unroll 1
    for (int i = 0; i < 32; ++i) {
        if (i < 31) {
            if constexpr (NDMA == 5)
                asm volatile("s_waitcnt vmcnt(5)" ::: "memory");  // oldest batch done
            else
                asm volatile("s_waitcnt vmcnt(4)" ::: "memory");
        } else {
            asm volatile("s_waitcnt vmcnt(0)" ::: "memory");      // final batch done
        }
        asm volatile("s_barrier" ::: "memory");                   // raw: no drain
        if (i < 30)                        // batch i+2 -> buf (i+2)%3 (WAR-safe)
            stage(i + 2, (i + 2) % 3);

        const char* buf = st + (i % 3) * BUFB;
        bf16x8 aF[4], bF[2];
        if constexpr (AF32) {
            const float* sA = (const float*)buf;
#pragma unroll
            for (int ii = 0; ii < 4; ++ii) {
                const int rb = (wr + ii * 16 + fr) * 32;
                f32x4 lo = *(const f32x4*)&sA[rb + s32];
                f32x4 hi = *(const f32x4*)&sA[rb + (s32 ^ 4)];
                aF[ii] = cvt8(lo, hi);
            }
        } else {
            const bf16* sA = (const bf16*)buf;
#pragma unroll
            for (int ii = 0; ii < 4; ++ii)
                aF[ii] = *(const bf16x8*)&sA[(wr + ii * 16 + fr) * 32 + q8];
        }
        if constexpr (BF32) {
            const float* sB = (const float*)(buf + ABYTES);
#pragma unroll
            for (int j = 0; j < 2; ++j) {
                const int rb = (wc + j * 16 + fr) * 32;
                f32x4 lo = *(const f32x4*)&sB[rb + s32];
                f32x4 hi = *(const f32x4*)&sB[rb + (s32 ^ 4)];
                bF[j] = cvt8(lo, hi);
            }
        } else {
            const bf16* sB = (const bf16*)(buf + ABYTES);
#pragma unroll
            for (int j = 0; j < 2; ++j)
                bF[j] = *(const bf16x8*)&sB[(wc + j * 16 + fr) * 32 + q8];
        }
#pragma unroll
        for (int ii = 0; ii < 4; ++ii)
#pragma unroll
            for (int j = 0; j < 2; ++j)
                acc[ii][j] = __builtin_amdgcn_mfma_f32_16x16x32_bf16(
                    aF[ii], bF[j], acc[ii][j], 0, 0, 0);
    }

    // epilogue: C/D layout col=lane&15, row=(lane>>4)*4+reg  [m91-verified]
#pragma unroll
    for (int i = 0; i < 4; ++i) {
#pragma unroll
        for (int j = 0; j < 2; ++j) {
            const int col = n0 + wc + j * 16 + (lane & 15);
#pragma unroll
            for (int r = 0; r < 4; ++r) {
                const int row = m0 + wr + i * 16 + (lane >> 4) * 4 + r;
                if (PERMUTE) {
                    const int b = row >> 11, t = row & 2047;
                    const int h = col >> 6,  k = col & 63;
                    const int rr = (b << 11) | (h << 7) | (t >> 4);
                    const int cc = ((t & 15) << 6) | k;
                    storeC(acc[i][j][r], &C[(size_t)rr * 1024 + cc]);
                } else {
                    storeC(acc[i][j][r], &C[(size_t)row * 1024 + col]);
                }
            }
        }
    }
}

extern "C" void kernel_launch(void* const* d_in, const int* in_sizes, int n_in,
                              void* d_out, int out_size, void* d_ws, size_t ws_size,
                              hipStream_t stream) {
    (void)in_sizes; (void)n_in; (void)out_size; (void)ws_size;
    // inputs (fp32): x, mask, Wq, Wk, Wv, Wo  (mask/Wq/Wk dead — see header)
    const float* x  = (const float*)d_in[0];
    const float* Wv = (const float*)d_in[4];
    const float* Wo = (const float*)d_in[5];
    float* out = (float*)d_out;

    bf16* WvT   = (bf16*)d_ws;                 // 1024*1024 bf16 = 2 MB
    bf16* vperm = WvT + 1024 * 1024;           // 8 MB   (total 10 MB)

    prep<<<256, 256, 0, stream>>>(Wv, WvT);
    // V = x @ Wv, written permuted (bf16); A = x fp32 direct
    gemm_bt<true,  true,  false, bf16 ><<<dim3(32, 16), 256, 0, stream>>>(x, WvT, vperm);
    // y = Vp @ Wo^T (fp32 out); B = Wo fp32 direct (row-major == Bt layout)
    gemm_bt<false, false, true,  float><<<dim3(32, 16), 256, 0, stream>>>(vperm, Wo, out);
}

// Round 3
// 115.443 us; speedup vs baseline: 1.0390x; 1.0390x over previous
//
#include <hip/hip_runtime.h>
#include <hip/hip_bf16.h>

// Problem constants: B=2, T=2048, D=1024, H=16, DK=64
// Math reduction: y = permute(x @ Wv) @ Wo^T  (softmax rowsum == 1 exactly;
// reference's einsum 'bhtl,bthd->bhtd' never contracts v with A over l, so
// o[b,h,t,:] = (sum_l A[b,h,t,l]) * v[b,t,h,:] = v[b,t,h,:]).
// Permute: V[b*2048+t][h*64+k] -> Vp[b*2048 + h*128 + t/16][(t%16)*64 + k]
// R13: fold x-cvt into gemm1 on the WRITE side (R12 failed on the read
// side): x fp32 -> regs (issued 2 steps ahead) -> cvt -> ds_write_b128 into
// the exact R10 bf16 LDS layout. MFMA-feed path unchanged from R10.
// 5 VM ops/step (4 A dwordx4 + 1 B DMA); window-counted vmcnt(5);
// lgkmcnt(0) before each barrier for ds_write cross-wave visibility.
// prep = Wv transpose + Wo cvt only (1280 blocks, ~10 MB).  gemm2 = R10.
// Ledger: R10 best 114.1; R11 (128x128) neutral; R12 (read-side fp32 LDS)
// +5.3; fixed harness overhead ~64 us; persistent fusion +152 us.

using bf16 = __hip_bfloat16;
typedef __attribute__((ext_vector_type(8))) short bf16x8;   // 8 bf16 = 4 VGPRs
typedef __attribute__((ext_vector_type(4))) float f32x4;

__device__ __forceinline__ void gld_lds16(const void* g, void* l) {
    // async global->LDS, 16B/lane; LDS dest = wave-uniform base + lane*16
    __builtin_amdgcn_global_load_lds(
        (const __attribute__((address_space(1))) void*)g,
        (__attribute__((address_space(3))) void*)l, 16, 0, 0);
}

__device__ __forceinline__ bf16x8 cvt8(f32x4 lo, f32x4 hi) {
    bf16 o[8] = {__float2bfloat16(lo[0]), __float2bfloat16(lo[1]),
                 __float2bfloat16(lo[2]), __float2bfloat16(lo[3]),
                 __float2bfloat16(hi[0]), __float2bfloat16(hi[1]),
                 __float2bfloat16(hi[2]), __float2bfloat16(hi[3])};
    return *(bf16x8*)o;
}

// ---- prep: Wv transpose+cvt (WvT[n][k]=bf16(Wv[k][n])) + Wo cvt -----------
__global__ __launch_bounds__(256) void prep(const float* __restrict__ Wv,
                                            const float* __restrict__ Wo,
                                            bf16* __restrict__ WvT,
                                            bf16* __restrict__ Wob) {
    __shared__ float tile[64][65];
    const int id = blockIdx.x;
    const int t  = threadIdx.x;
    if (id < 256) {                       // Wv transpose (16x16 tiles of 64x64)
        const int bx = id & 15, by = id >> 4;
        const int c = t & 63, r4 = t >> 6;
#pragma unroll
        for (int p = 0; p < 16; ++p) {
            int r = p * 4 + r4;
            tile[r][c] = Wv[(size_t)(by * 64 + r) * 1024 + bx * 64 + c];
        }
        __syncthreads();
#pragma unroll
        for (int p = 0; p < 16; ++p) {
            int r = p * 4 + r4;
            WvT[(size_t)(bx * 64 + r) * 1024 + by * 64 + c] = __float2bfloat16(tile[c][r]);
        }
    } else {                              // Wo -> bf16, float4 per thread
        const int i = (id - 256) * 256 + t;
        const float4 v = ((const float4*)Wo)[i];
        bf16 o[4] = {__float2bfloat16(v.x), __float2bfloat16(v.y),
                     __float2bfloat16(v.z), __float2bfloat16(v.w)};
        ((ulong1*)Wob)[i] = *(ulong1*)o;
    }
}

__device__ __forceinline__ void storeC(float v, bf16* p)  { *p = __float2bfloat16(v); }
__device__ __forceinline__ void storeC(float v, float* p) { *p = v; }

// ---------------- gemm1: C = x(fp32, Mx1024) * Bt(bf16, Nx1024)^T ----------
// A staged via regs (fp32 global -> cvt -> ds_write bf16), B via DMA.
// 128x64 tile / 256 threads; 4 waves 2x2, each 64x32 = 4x2 accs.
// Triple-buffered LDS identical to R10; window-counted vmcnt.
template <bool PERMUTE, typename OutT>
__global__ __launch_bounds__(256) void gemm_xa(const float* __restrict__ A32,
                                               const bf16* __restrict__ Bt,
                                               OutT* __restrict__ C) {
    __shared__ __align__(16) bf16 st[3][6144];    // per buf: A 8KB + B 4KB

    const int tid  = threadIdx.x;
    const int wave = tid >> 6;
    const int lane = tid & 63;
    const int m0 = blockIdx.x * 128;
    const int n0 = blockIdx.y * 64;

    const int wr = (wave >> 1) * 64;      // wave quadrant of 128x64 tile
    const int wc = (wave & 1) * 32;

    // A reg-staging: thread covers rows (tid>>2) and (tid>>2)+64, slot tid&3.
    // LDS slot s of row r holds global chunk s ^ ((r>>1)&3)  (same as R10 DMA).
    const int cg = (((tid & 3) ^ ((tid >> 3) & 3)) & 3) * 8;   // float offset
    const float* gx = A32 + (size_t)(m0 + (tid >> 2)) * 1024 + cg;
    const int la = (tid >> 2) * 64 + (tid & 3) * 16;           // LDS byte dest

    // B staging (bf16 DMA), same as R10
    const bf16* gB = Bt + (size_t)(n0 + (tid >> 2)) * 1024
                   + ((((tid & 3) ^ ((tid >> 3) & 3)) & 3) * 8);
    const int woff = wave * 512;          // elems, wave-uniform LDS base

    f32x4 rA[2][4];                       // 2-deep A pipeline (32 VGPR)
    f32x4 acc[4][2];
#pragma unroll
    for (int i = 0; i < 4; ++i)
#pragma unroll
        for (int j = 0; j < 2; ++j)
            acc[i][j] = (f32x4){0.f, 0.f, 0.f, 0.f};

    const int fr = lane & 15;
    const int q8 = (((lane >> 4) ^ (lane >> 1)) & 3) * 8;      // swizzled slot

    // ---- prologue: tiles 0,1 -> LDS now; tiles 2,3 + B0,B1 in flight ----
    {
        const float* p0 = gx;
        rA[0][0] = *(const f32x4*)p0;
        rA[0][1] = *(const f32x4*)(p0 + 4);
        rA[0][2] = *(const f32x4*)(p0 + 65536);
        rA[0][3] = *(const f32x4*)(p0 + 65536 + 4);
        const float* p1 = gx + 32;
        rA[1][0] = *(const f32x4*)p1;
        rA[1][1] = *(const f32x4*)(p1 + 4);
        rA[1][2] = *(const f32x4*)(p1 + 65536);
        rA[1][3] = *(const f32x4*)(p1 + 65536 + 4);
        char* d0 = (char*)st[0];
        *(bf16x8*)(d0 + la)        = cvt8(rA[0][0], rA[0][1]);
        *(bf16x8*)(d0 + la + 4096) = cvt8(rA[0][2], rA[0][3]);
        char* d1 = (char*)st[1];
        *(bf16x8*)(d1 + la)        = cvt8(rA[1][0], rA[1][1]);
        *(bf16x8*)(d1 + la + 4096) = cvt8(rA[1][2], rA[1][3]);
        asm volatile("" ::: "memory");
        // group X: A tile2 (4 ops) + B0 DMA (1 op)
        const float* p2 = gx + 64;
        rA[0][0] = *(const f32x4*)p2;
        rA[0][1] = *(const f32x4*)(p2 + 4);
        rA[0][2] = *(const f32x4*)(p2 + 65536);
        rA[0][3] = *(const f32x4*)(p2 + 65536 + 4);
        gld_lds16(gB, st[0] + 4096 + woff);
        asm volatile("" ::: "memory");
        // group Y: A tile3 (4 ops) + B1 DMA (1 op)
        const float* p3 = gx + 96;
        rA[1][0] = *(const f32x4*)p3;
        rA[1][1] = *(const f32x4*)(p3 + 4);
        rA[1][2] = *(const f32x4*)(p3 + 65536);
        rA[1][3] = *(const f32x4*)(p3 + 65536 + 4);
        gld_lds16(gB + 32, st[1] + 4096 + woff);
    }

    // steady state: at top of step i, outstanding = steps i-1,i-2 (5 ops each);
    // vmcnt(5) drains step i-2 (A-loads for this step's ds_write + B for this
    // step's MFMA). Tail: A-issues stop at i=27, B/write at i=29.
#pragma unroll 2
    for (int i = 0; i < 32; ++i) {
        if (i <= 28)
            asm volatile("s_waitcnt vmcnt(5)" ::: "memory");
        else if (i <= 30)
            asm volatile("s_waitcnt vmcnt(1)" ::: "memory");
        else
            asm volatile("s_waitcnt vmcnt(0)" ::: "memory");
        asm volatile("s_waitcnt lgkmcnt(0)" ::: "memory");   // ds_writes visible
        asm volatile("s_barrier" ::: "memory");

        f32x4 (&rW)[4] = rA[i & 1];       // tile i+2 (loaded 2 steps ago)
        if (i <= 29) {                    // ds_write tile i+2 -> buf (i+2)%3
            char* dA = (char*)st[(i + 2) % 3];
            *(bf16x8*)(dA + la)        = cvt8(rW[0], rW[1]);
            *(bf16x8*)(dA + la + 4096) = cvt8(rW[2], rW[3]);
        }
        if (i <= 27) {                    // reload rW with tile i+4
            const float* p = gx + (i + 4) * 32;
            rW[0] = *(const f32x4*)p;
            rW[1] = *(const f32x4*)(p + 4);
            rW[2] = *(const f32x4*)(p + 65536);
            rW[3] = *(const f32x4*)(p + 65536 + 4);
        }
        if (i <= 29)                      // B DMA tile i+2 -> buf (i+2)%3
            gld_lds16(gB + (i + 2) * 32, st[(i + 2) % 3] + 4096 + woff);

        const bf16* sAb = st[i % 3];
        const bf16* sBb = st[i % 3] + 4096;
        bf16x8 aF[4], bF[2];
#pragma unroll
        for (int ii = 0; ii < 4; ++ii)
            aF[ii] = *(const bf16x8*)&sAb[(wr + ii * 16 + fr) * 32 + q8];
#pragma unroll
        for (int j = 0; j < 2; ++j)
            bF[j] = *(const bf16x8*)&sBb[(wc + j * 16 + fr) * 32 + q8];
#pragma unroll
        for (int ii = 0; ii < 4; ++ii)
#pragma unroll
            for (int j = 0; j < 2; ++j)
                acc[ii][j] = __builtin_amdgcn_mfma_f32_16x16x32_bf16(
                    aF[ii], bF[j], acc[ii][j], 0, 0, 0);
    }

    // epilogue: C/D layout col=lane&15, row=(lane>>4)*4+reg  [m91-verified]
#pragma unroll
    for (int i = 0; i < 4; ++i) {
#pragma unroll
        for (int j = 0; j < 2; ++j) {
            const int col = n0 + wc + j * 16 + (lane & 15);
#pragma unroll
            for (int r = 0; r < 4; ++r) {
                const int row = m0 + wr + i * 16 + (lane >> 4) * 4 + r;
                if (PERMUTE) {
                    const int b = row >> 11, t = row & 2047;
                    const int h = col >> 6,  k = col & 63;
                    const int rr = (b << 11) | (h << 7) | (t >> 4);
                    const int cc = ((t & 15) << 6) | k;
                    storeC(acc[i][j][r], &C[(size_t)rr * 1024 + cc]);
                } else {
                    storeC(acc[i][j][r], &C[(size_t)row * 1024 + col]);
                }
            }
        }
    }
}

// ---------------- gemm2: R10 verbatim (bf16 A via DMA, bf16 B via DMA) -----
template <bool PERMUTE, typename OutT>
__global__ __launch_bounds__(256) void gemm_bt(const bf16* __restrict__ A,
                                               const bf16* __restrict__ Bt,
                                               OutT* __restrict__ C) {
    __shared__ __align__(16) bf16 st[3][6144];    // 3 x 12 KB = 36 KB

    const int tid  = threadIdx.x;
    const int wave = tid >> 6;
    const int lane = tid & 63;
    const int m0 = blockIdx.x * 128;
    const int n0 = blockIdx.y * 64;

    const int wr = (wave >> 1) * 64;      // wave quadrant of 128x64 tile
    const int wc = (wave & 1) * 32;

    const int srow = tid >> 2;
    const int scol = (((tid & 3) ^ ((tid >> 3) & 3)) & 3) * 8;
    const bf16* gA = A  + (size_t)(m0 + srow) * 1024 + scol;
    const bf16* gB = Bt + (size_t)(n0 + srow) * 1024 + scol;
    const int woff = wave * 512;          // elems, wave-uniform LDS base

    f32x4 acc[4][2];
#pragma unroll
    for (int i = 0; i < 4; ++i)
#pragma unroll
        for (int j = 0; j < 2; ++j)
            acc[i][j] = (f32x4){0.f, 0.f, 0.f, 0.f};

    const int fr = lane & 15;
    const int q8 = ((((lane >> 4) ^ (lane >> 1)) & 3)) * 8;  // swizzled slot

#pragma unroll
    for (int b = 0; b < 2; ++b) {
        bf16* s = st[b];
        const int kt = b * 32;
        gld_lds16(gA + kt,             s + woff);
        gld_lds16(gA + kt + 64 * 1024, s + 2048 + woff);
        gld_lds16(gB + kt,             s + 4096 + woff);
    }

#pragma unroll 1
    for (int i = 0; i < 32; ++i) {
        if (i < 31)
            asm volatile("s_waitcnt vmcnt(3)" ::: "memory");   // oldest batch done
        else
            asm volatile("s_waitcnt vmcnt(0)" ::: "memory");   // final batch done
        asm volatile("s_barrier" ::: "memory");                // raw: no drain
        if (i < 30) {                     // batch i+2 -> buf (i+2)%3 (WAR-safe)
            const int kt = (i + 2) * 32;
            bf16* s = st[(i + 2) % 3];
            gld_lds16(gA + kt,             s + woff);
            gld_lds16(gA + kt + 64 * 1024, s + 2048 + woff);
            gld_lds16(gB + kt,             s + 4096 + woff);
        }

        const bf16* sAb = st[i % 3];
        const bf16* sBb = st[i % 3] + 4096;
        bf16x8 aF[4], bF[2];
#pragma unroll
        for (int ii = 0; ii < 4; ++ii)
            aF[ii] = *(const bf16x8*)&sAb[(wr + ii * 16 + fr) * 32 + q8];
#pragma unroll
        for (int j = 0; j < 2; ++j)
            bF[j] = *(const bf16x8*)&sBb[(wc + j * 16 + fr) * 32 + q8];
#pragma unroll
        for (int ii = 0; ii < 4; ++ii)
#pragma unroll
            for (int j = 0; j < 2; ++j)
                acc[ii][j] = __builtin_amdgcn_mfma_f32_16x16x32_bf16(
                    aF[ii], bF[j], acc[ii][j], 0, 0, 0);
    }

#pragma unroll
    for (int i = 0; i < 4; ++i) {
#pragma unroll
        for (int j = 0; j < 2; ++j) {
            const int col = n0 + wc + j * 16 + (lane & 15);
#pragma unroll
            for (int r = 0; r < 4; ++r) {
                const int row = m0 + wr + i * 16 + (lane >> 4) * 4 + r;
                if (PERMUTE) {
                    const int b = row >> 11, t = row & 2047;
                    const int h = col >> 6,  k = col & 63;
                    const int rr = (b << 11) | (h << 7) | (t >> 4);
                    const int cc = ((t & 15) << 6) | k;
                    storeC(acc[i][j][r], &C[(size_t)rr * 1024 + cc]);
                } else {
                    storeC(acc[i][j][r], &C[(size_t)row * 1024 + col]);
                }
            }
        }
    }
}

extern "C" void kernel_launch(void* const* d_in, const int* in_sizes, int n_in,
                              void* d_out, int out_size, void* d_ws, size_t ws_size,
                              hipStream_t stream) {
    (void)in_sizes; (void)n_in; (void)out_size; (void)ws_size;
    // inputs (fp32): x, mask, Wq, Wk, Wv, Wo  (mask/Wq/Wk dead — see header)
    const float* x  = (const float*)d_in[0];
    const float* Wv = (const float*)d_in[4];
    const float* Wo = (const float*)d_in[5];
    float* out = (float*)d_out;

    bf16* WvT   = (bf16*)d_ws;                 // 2 MB
    bf16* Wob   = WvT + 1024 * 1024;           // 2 MB
    bf16* vperm = Wob + 1024 * 1024;           // 8 MB   (total 12 MB)

    prep<<<1280, 256, 0, stream>>>(Wv, Wo, WvT, Wob);
    // V = x @ Wv (A = x fp32 reg-staged), written permuted (bf16)
    gemm_xa<true,  bf16 ><<<dim3(32, 16), 256, 0, stream>>>(x, WvT, vperm);
    // y = Vp @ Wo^T  (fp32 output)
    gemm_bt<false, float><<<dim3(32, 16), 256, 0, stream>>>(vperm, Wob, out);
}

// Round 4
// 114.664 us; speedup vs baseline: 1.0461x; 1.0068x over previous
//
#include <hip/hip_runtime.h>
#include <hip/hip_bf16.h>

// Problem constants: B=2, T=2048, D=1024, H=16, DK=64
// Math reduction: y = permute(x @ Wv) @ Wo^T  (softmax rowsum == 1 exactly;
// reference's einsum 'bhtl,bthd->bhtd' never contracts v with A over l, so
// o[b,h,t,:] = (sum_l A[b,h,t,l]) * v[b,t,h,:] = v[b,t,h,:]).
// Permute: V[b*2048+t][h*64+k] -> Vp[b*2048 + h*128 + t/16][(t%16)*64 + k]
// Inputs/outputs FP32 (reference dtype); internal bf16 MFMA, fp32 accum.
// R14 = FINAL REVERT to R10 (best measured: 114.09 us).
// Closing ledger (two sessions, ~12 structural variants):
//   R9  32x32 MFMA shape            +5.2 us
//   R11 128x128 tile (2x reuse)     +0.6 us (neutral; insensitive to reuse
//                                    AND to halved occupancy)
//   R12 read-side fp32 LDS + cvt    +5.8 us (dependent VALU on MFMA feed)
//   R13 write-side reg-staged cvt   +1.3 us (-20 MB HBM absorbed to zero)
//   occupancy/dbuf/swizzle/vmcnt/persistent-fusion: <=2.6 / +152 us
// Conclusion: the 3 short dependent kernels are ramp/latency-floor bound
// (~50 us), plus ~64 us harness-fixed (256 MiB re-poison fill ~44 us +
// launch gaps). No steerable axis (LDS BW, HBM bytes, occupancy, reuse,
// conversion placement) moves the total; plateau reached.

using bf16 = __hip_bfloat16;
typedef __attribute__((ext_vector_type(8))) short bf16x8;   // 8 bf16 = 4 VGPRs
typedef __attribute__((ext_vector_type(4))) float f32x4;

__device__ __forceinline__ void gld_lds16(const void* g, void* l) {
    // async global->LDS, 16B/lane; LDS dest = wave-uniform base + lane*16
    __builtin_amdgcn_global_load_lds(
        (const __attribute__((address_space(1))) void*)g,
        (__attribute__((address_space(3))) void*)l, 16, 0, 0);
}

// ---- fused prep: Wv transpose+cvt | x cvt | Wo cvt, one dispatch ----------
__global__ __launch_bounds__(256) void prep(const float* __restrict__ x,
                                            const float* __restrict__ Wv,
                                            const float* __restrict__ Wo,
                                            bf16* __restrict__ xb,
                                            bf16* __restrict__ WvT,
                                            bf16* __restrict__ Wob) {
    __shared__ float tile[64][65];
    const int id = blockIdx.x;
    const int t  = threadIdx.x;
    if (id < 256) {                       // Wv transpose+convert (64x64 tile)
        const int bx = id & 15, by = id >> 4;
        const int c = t & 63, r4 = t >> 6;
#pragma unroll
        for (int p = 0; p < 16; ++p) {
            int r = p * 4 + r4;
            tile[r][c] = Wv[(size_t)(by * 64 + r) * 1024 + bx * 64 + c];
        }
        __syncthreads();
#pragma unroll
        for (int p = 0; p < 16; ++p) {
            int r = p * 4 + r4;
            WvT[(size_t)(bx * 64 + r) * 1024 + by * 64 + c] = __float2bfloat16(tile[c][r]);
        }
    } else if (id < 4352) {               // x -> bf16, float4 per thread
        const int i = (id - 256) * 256 + t;
        const float4 v = ((const float4*)x)[i];
        bf16 o[4] = {__float2bfloat16(v.x), __float2bfloat16(v.y),
                     __float2bfloat16(v.z), __float2bfloat16(v.w)};
        ((ulong1*)xb)[i] = *(ulong1*)o;
    } else {                              // Wo -> bf16
        const int i = (id - 4352) * 256 + t;
        const float4 v = ((const float4*)Wo)[i];
        bf16 o[4] = {__float2bfloat16(v.x), __float2bfloat16(v.y),
                     __float2bfloat16(v.z), __float2bfloat16(v.w)};
        ((ulong1*)Wob)[i] = *(ulong1*)o;
    }
}

// ---------------- GEMM  C = A(Mx1024) * Bt(Nx1024)^T -----------------------
// A, Bt bf16 row-major [.][K]: both operands K-contiguous.
// 128x64 tile / 256 threads; 4 waves 2x2, each 64x32 = 4x2 accs.
// Triple-buffered LDS, 2 DMA batches in flight, raw s_barrier + vmcnt(3).
__device__ __forceinline__ void storeC(float v, bf16* p)  { *p = __float2bfloat16(v); }
__device__ __forceinline__ void storeC(float v, float* p) { *p = v; }

template <bool PERMUTE, typename OutT>
__global__ __launch_bounds__(256) void gemm_bt(const bf16* __restrict__ A,
                                               const bf16* __restrict__ Bt,
                                               OutT* __restrict__ C) {
    __shared__ __align__(16) bf16 st[3][6144];    // 3 x 12 KB = 36 KB

    const int tid  = threadIdx.x;
    const int wave = tid >> 6;
    const int lane = tid & 63;
    const int m0 = blockIdx.x * 128;
    const int n0 = blockIdx.y * 64;

    const int wr = (wave >> 1) * 64;      // wave quadrant of 128x64 tile
    const int wc = (wave & 1) * 32;

    // staging: thread t covers tile row tid>>2, 16B chunk slot tid&3.
    // Swizzle: slot s of row r holds global chunk g = s ^ ((r>>1)&3).
    const int srow = tid >> 2;
    const int scol = (((tid & 3) ^ ((tid >> 3) & 3)) & 3) * 8;
    const bf16* gA = A  + (size_t)(m0 + srow) * 1024 + scol;
    const bf16* gB = Bt + (size_t)(n0 + srow) * 1024 + scol;
    const int woff = wave * 512;          // elems, wave-uniform LDS base

    f32x4 acc[4][2];
#pragma unroll
    for (int i = 0; i < 4; ++i)
#pragma unroll
        for (int j = 0; j < 2; ++j)
            acc[i][j] = (f32x4){0.f, 0.f, 0.f, 0.f};

    const int fr = lane & 15;
    const int q8 = ((((lane >> 4) ^ (lane >> 1)) & 3)) * 8;  // swizzled slot

    // prologue: batches 0,1 -> bufs 0,1 (6 DMAs outstanding per wave)
#pragma unroll
    for (int b = 0; b < 2; ++b) {
        bf16* s = st[b];
        const int kt = b * 32;
        gld_lds16(gA + kt,             s + woff);
        gld_lds16(gA + kt + 64 * 1024, s + 2048 + woff);
        gld_lds16(gB + kt,             s + 4096 + woff);
    }

#pragma unroll 1
    for (int i = 0; i < 32; ++i) {
        if (i < 31)
            asm volatile("s_waitcnt vmcnt(3)" ::: "memory");   // oldest batch done
        else
            asm volatile("s_waitcnt vmcnt(0)" ::: "memory");   // final batch done
        asm volatile("s_barrier" ::: "memory");                // raw: no vmcnt(0) drain
        if (i < 30) {                     // batch i+2 -> buf (i+2)%3 (post-barrier: WAR-safe)
            const int kt = (i + 2) * 32;
            bf16* s = st[(i + 2) % 3];
            gld_lds16(gA + kt,             s + woff);
            gld_lds16(gA + kt + 64 * 1024, s + 2048 + woff);
            gld_lds16(gB + kt,             s + 4096 + woff);
        }

        const bf16* sAb = st[i % 3];
        const bf16* sBb = st[i % 3] + 4096;
        bf16x8 aF[4], bF[2];
#pragma unroll
        for (int ii = 0; ii < 4; ++ii)
            aF[ii] = *(const bf16x8*)&sAb[(wr + ii * 16 + fr) * 32 + q8];
#pragma unroll
        for (int j = 0; j < 2; ++j)
            bF[j] = *(const bf16x8*)&sBb[(wc + j * 16 + fr) * 32 + q8];
#pragma unroll
        for (int ii = 0; ii < 4; ++ii)
#pragma unroll
            for (int j = 0; j < 2; ++j)
                acc[ii][j] = __builtin_amdgcn_mfma_f32_16x16x32_bf16(
                    aF[ii], bF[j], acc[ii][j], 0, 0, 0);
    }

    // epilogue: C/D layout col=lane&15, row=(lane>>4)*4+reg  [m91-verified]
#pragma unroll
    for (int i = 0; i < 4; ++i) {
#pragma unroll
        for (int j = 0; j < 2; ++j) {
            const int col = n0 + wc + j * 16 + (lane & 15);
#pragma unroll
            for (int r = 0; r < 4; ++r) {
                const int row = m0 + wr + i * 16 + (lane >> 4) * 4 + r;
                if (PERMUTE) {
                    const int b = row >> 11, t = row & 2047;
                    const int h = col >> 6,  k = col & 63;
                    const int rr = (b << 11) | (h << 7) | (t >> 4);
                    const int cc = ((t & 15) << 6) | k;
                    storeC(acc[i][j][r], &C[(size_t)rr * 1024 + cc]);
                } else {
                    storeC(acc[i][j][r], &C[(size_t)row * 1024 + col]);
                }
            }
        }
    }
}

extern "C" void kernel_launch(void* const* d_in, const int* in_sizes, int n_in,
                              void* d_out, int out_size, void* d_ws, size_t ws_size,
                              hipStream_t stream) {
    (void)in_sizes; (void)n_in; (void)out_size; (void)ws_size;
    // inputs (fp32): x, mask, Wq, Wk, Wv, Wo  (mask/Wq/Wk dead — see header)
    const float* x  = (const float*)d_in[0];
    const float* Wv = (const float*)d_in[4];
    const float* Wo = (const float*)d_in[5];
    float* out = (float*)d_out;

    bf16* xb    = (bf16*)d_ws;                 // 4096*1024 bf16 = 8 MB
    bf16* WvT   = xb    + 4096 * 1024;         // 2 MB
    bf16* Wob   = WvT   + 1024 * 1024;         // 2 MB
    bf16* vperm = Wob   + 1024 * 1024;         // 8 MB   (total 20 MB)

    prep<<<5376, 256, 0, stream>>>(x, Wv, Wo, xb, WvT, Wob);
    // V = x @ Wv, written permuted (bf16)
    gemm_bt<true,  bf16 ><<<dim3(32, 16), 256, 0, stream>>>(xb, WvT, vperm);
    // y = Vp @ Wo^T  (fp32 output)
    gemm_bt<false, float><<<dim3(32, 16), 256, 0, stream>>>(vperm, Wob, out);
}